// Round 1
// baseline (77.605 us; speedup 1.0000x reference)
//
#include <hip/hip_runtime.h>
#include <hip/hip_bf16.h>

// Problem constants (fixed by setup_inputs): B=16, N=96.
// Factorization:
//   f[b,x,y]   = exp(-0.5*d^2) * tanh(1 - d/5)^3
//   g[b,x,y,:] = r_vec[b,x,y,:] * f / d
//   out[b,i]   = sum_{j,k} f[i,k] * ( f[i,j]*f[j,k] + dot(g[i,j], g[j,k]) )
// Workspace W[b][row][kpad=128] = float4(f, g0, g1, g2); cols 96..127 zeroed.

#define B 16
#define N 96
#define KP 128           // padded k dimension (zero-filled)
#define TI 4             // i-rows per block in pass 2
#define P2_THREADS 128   // 2 waves; lane == k

__global__ void g4_prep(const float* __restrict__ dv,
                        const float* __restrict__ dist,
                        float4* __restrict__ W) {
    int idx = blockIdx.x * blockDim.x + threadIdx.x;   // 0 .. B*N*KP-1
    if (idx >= B * N * KP) return;
    int k   = idx & (KP - 1);
    int row = idx >> 7;            // b*N + i
    float4 w = make_float4(0.f, 0.f, 0.f, 0.f);
    if (k < N) {
        int src = row * N + k;
        float d = dist[src];
        float r = tanhf(1.0f - d * 0.2f);
        float R = r * r * r;
        float f = expf(-0.5f * d * d) * R;
        float q = f / d;
        w.x = f;
        w.y = dv[src * 3 + 0] * q;
        w.z = dv[src * 3 + 1] * q;
        w.w = dv[src * 3 + 2] * q;
    }
    W[idx] = w;
}

__global__ __launch_bounds__(P2_THREADS)
void g4_contract(const float4* __restrict__ W, float* __restrict__ out) {
    // block: b = blockIdx.x / (N/TI), i0 = (blockIdx.x % (N/TI)) * TI
    const int b  = blockIdx.x / (N / TI);
    const int i0 = (blockIdx.x % (N / TI)) * TI;
    const int t  = threadIdx.x;          // lane == k in [0,128)

    __shared__ float4 rowI[TI][N];       // (f,g) for rows i0..i0+TI-1, cols j

    const float4* Wb = W + (size_t)b * N * KP;

    // preload the TI i-rows (cols 0..95) into LDS
    for (int e = t; e < TI * N; e += P2_THREADS) {
        int ii = e / N, j = e % N;
        rowI[ii][j] = Wb[(i0 + ii) * KP + j];
    }

    // per-thread f[i,k] values (pad lanes read zeros)
    float fik[TI];
#pragma unroll
    for (int ii = 0; ii < TI; ++ii)
        fik[ii] = Wb[(i0 + ii) * KP + t].x;

    __syncthreads();

    float acc[TI] = {0.f, 0.f, 0.f, 0.f};
#pragma unroll 4
    for (int j = 0; j < N; ++j) {
        float4 wj = Wb[j * KP + t];      // (f[j,k], g[j,k]) for this lane's k
#pragma unroll
        for (int ii = 0; ii < TI; ++ii) {
            float4 ri = rowI[ii][j];     // uniform broadcast (f[i,j], g[i,j])
            float inner = ri.x * wj.x + ri.y * wj.y + ri.z * wj.z + ri.w * wj.w;
            acc[ii] = fmaf(fik[ii], inner, acc[ii]);
        }
    }

    // block reduction over 128 lanes (2 waves)
    __shared__ float red[TI][2];
#pragma unroll
    for (int ii = 0; ii < TI; ++ii) {
        float v = acc[ii];
        for (int off = 32; off > 0; off >>= 1)
            v += __shfl_down(v, off);    // width = 64 (wave)
        if ((t & 63) == 0) red[ii][t >> 6] = v;
    }
    __syncthreads();
    if (t < TI) {
        out[b * N + i0 + t] = red[t][0] + red[t][1];
    }
}

extern "C" void kernel_launch(void* const* d_in, const int* in_sizes, int n_in,
                              void* d_out, int out_size, void* d_ws, size_t ws_size,
                              hipStream_t stream) {
    const float* dv   = (const float*)d_in[0];   // (B,N,N,3) f32
    const float* dist = (const float*)d_in[1];   // (B,N,N)   f32
    float*  out = (float*)d_out;                 // (B,N)     f32
    float4* W   = (float4*)d_ws;                 // B*N*KP float4 = 3 MiB

    {
        int total = B * N * KP;
        int thr = 256;
        int blk = (total + thr - 1) / thr;
        g4_prep<<<blk, thr, 0, stream>>>(dv, dist, W);
    }
    {
        int blk = B * (N / TI);                  // 384 blocks
        g4_contract<<<blk, P2_THREADS, 0, stream>>>(W, out);
    }
}

// Round 2
// 68.640 us; speedup vs baseline: 1.1306x; 1.1306x over previous
//
#include <hip/hip_runtime.h>
#include <hip/hip_bf16.h>

// Problem constants (fixed by setup_inputs): B=16, N=96.
// Factorization (zeta=1, lambda=1, coeff=1):
//   f[b,x,y]   = exp(-0.5*d^2) * tanh(1 - d/5)^3
//   g[b,x,y,:] = r_vec[b,x,y,:] * f / d
//   out[b,i]   = sum_{j,k} f[i,k] * ( f[i,j]*f[j,k] + dot(g[i,j], g[j,k]) )
// Workspace W[b][row][kpad=128] = float4(f, g0, g1, g2); cols 96..127 zeroed.
// Pass 2 splits the j-range 4-way across blocks (occupancy: 1536 blocks,
// 3 waves/SIMD) and accumulates with atomicAdd; pass 1 zeroes d_out.

#define B 16
#define N 96
#define KP 128           // padded k dimension (zero-filled)
#define TI 4             // i-rows per block in pass 2
#define JS 4             // j-range splits per (b, i-chunk)
#define JC (N / JS)      // 24 j's per block
#define P2_THREADS 128   // 2 waves; lane == k

__global__ void g4_prep(const float* __restrict__ dv,
                        const float* __restrict__ dist,
                        float4* __restrict__ W,
                        float* __restrict__ out) {
    int idx = blockIdx.x * blockDim.x + threadIdx.x;   // 0 .. B*N*KP-1
    if (idx < B * N) out[idx] = 0.f;                   // zero for pass-2 atomics
    if (idx >= B * N * KP) return;
    int k   = idx & (KP - 1);
    int row = idx >> 7;            // b*N + i
    float4 w = make_float4(0.f, 0.f, 0.f, 0.f);
    if (k < N) {
        int src = row * N + k;
        float d = dist[src];
        // tanh(1 - d/5): argument in (0.8, 1.0) -> branch-free formula
        float e2 = expf(-2.0f * (1.0f - d * 0.2f));
        float r  = (1.0f - e2) / (1.0f + e2);
        float f  = expf(-0.5f * d * d) * r * r * r;
        float q  = f / d;
        w.x = f;
        w.y = dv[src * 3 + 0] * q;
        w.z = dv[src * 3 + 1] * q;
        w.w = dv[src * 3 + 2] * q;
    }
    W[idx] = w;
}

__global__ __launch_bounds__(P2_THREADS)
void g4_contract(const float4* __restrict__ W, float* __restrict__ out) {
    const int bi   = blockIdx.x;           // 0 .. B*(N/TI)*JS-1
    const int js   = bi % JS;
    const int rest = bi / JS;
    const int b    = rest / (N / TI);
    const int i0   = (rest % (N / TI)) * TI;
    const int j0   = js * JC;
    const int t    = threadIdx.x;          // lane == k in [0,128)

    __shared__ float4 rowI[TI][JC];        // (f,g) for rows i0.., cols j0..j0+JC

    const float4* Wb = W + (size_t)b * N * KP;

    for (int e = t; e < TI * JC; e += P2_THREADS) {
        int ii = e / JC, jj = e % JC;
        rowI[ii][jj] = Wb[(i0 + ii) * KP + j0 + jj];
    }

    float fik[TI];
#pragma unroll
    for (int ii = 0; ii < TI; ++ii)
        fik[ii] = Wb[(i0 + ii) * KP + t].x;   // pad lanes read zeros

    __syncthreads();

    float acc[TI] = {0.f, 0.f, 0.f, 0.f};
#pragma unroll 4
    for (int jj = 0; jj < JC; ++jj) {
        float4 wj = Wb[(j0 + jj) * KP + t];   // (f[j,k], g[j,k]) for lane's k
#pragma unroll
        for (int ii = 0; ii < TI; ++ii) {
            float4 ri = rowI[ii][jj];         // wave-uniform broadcast
            float inner = ri.x * wj.x + ri.y * wj.y + ri.z * wj.z + ri.w * wj.w;
            acc[ii] = fmaf(fik[ii], inner, acc[ii]);
        }
    }

    // block reduction over 128 lanes (2 waves)
    __shared__ float red[TI][2];
#pragma unroll
    for (int ii = 0; ii < TI; ++ii) {
        float v = acc[ii];
#pragma unroll
        for (int off = 32; off > 0; off >>= 1)
            v += __shfl_down(v, off);         // 6 steps cover the 64-lane wave
        if ((t & 63) == 0) red[ii][t >> 6] = v;
    }
    __syncthreads();
    if (t < TI)
        atomicAdd(&out[b * N + i0 + t], red[t][0] + red[t][1]);
}

extern "C" void kernel_launch(void* const* d_in, const int* in_sizes, int n_in,
                              void* d_out, int out_size, void* d_ws, size_t ws_size,
                              hipStream_t stream) {
    const float* dv   = (const float*)d_in[0];   // (B,N,N,3) f32
    const float* dist = (const float*)d_in[1];   // (B,N,N)   f32
    float*  out = (float*)d_out;                 // (B,N)     f32
    float4* W   = (float4*)d_ws;                 // B*N*KP float4 = 3 MiB

    {
        int total = B * N * KP;                  // 196608
        int thr = 256;
        int blk = (total + thr - 1) / thr;       // 768
        g4_prep<<<blk, thr, 0, stream>>>(dv, dist, W, out);
    }
    {
        int blk = B * (N / TI) * JS;             // 1536 blocks
        g4_contract<<<blk, P2_THREADS, 0, stream>>>(W, out);
    }
}